// Round 5
// baseline (163.282 us; speedup 1.0000x reference)
//
#include <hip/hip_runtime.h>

// DPQ network: response argmax (op_sel packed-f32 FMA, LDS centroids) + codebook-gather GEMM (bf16 MFMA)
// B=32768, C=32, K=256, D_SUB=16, D_IN=512, D_OUT=512

#define NB 32768
#define NC 32
#define NK 256
#define NDS 16
#define NDIN 512
#define NDOUT 512

typedef __attribute__((ext_vector_type(8))) short s8v;   // 8 bf16 in 4 VGPRs
typedef __attribute__((ext_vector_type(4))) float f4v;   // MFMA accumulator
typedef __attribute__((ext_vector_type(2))) float f2v;   // packed f32 pair (v_pk_*_f32)

__device__ __forceinline__ unsigned short f2bf(float f) {
  unsigned int u = __float_as_uint(f);
  u += 0x7fffu + ((u >> 16) & 1u);   // RNE
  return (unsigned short)(u >> 16);
}

__device__ __forceinline__ void gload16(const void* g, void* l) {
  __builtin_amdgcn_global_load_lds(
      (const __attribute__((address_space(1))) void*)g,
      (__attribute__((address_space(3))) void*)l, 16, 0, 0);
}

// Packed f32 FMA with op_sel: input pair `in` = {bLo_d, bHi_d} (two b's, one d),
// centroid pair `cp` = {c_d, c_{d+1}}; LO variant broadcasts cp.lo to both
// halves, HI variant broadcasts cp.hi. acc = {dot_bLo, dot_bHi}.
// Pure register ops (no memory clobber) -> scheduler may reorder freely.
#define PKMUL_LO(acc, in, cp) \
  asm("v_pk_mul_f32 %0, %1, %2 op_sel:[0,0] op_sel_hi:[1,0]" : "=v"(acc) : "v"(in), "v"(cp))
#define PKFMA_LO(acc, in, cp) \
  asm("v_pk_fma_f32 %0, %1, %2, %0 op_sel:[0,0,0] op_sel_hi:[1,0,1]" : "+v"(acc) : "v"(in), "v"(cp))
#define PKFMA_HI(acc, in, cp) \
  asm("v_pk_fma_f32 %0, %1, %2, %0 op_sel:[0,1,0] op_sel_hi:[1,1,1]" : "+v"(acc) : "v"(in), "v"(cp))

// ---------------------------------------------------------------------------
// Kernel 0: Wt[n][k] = bf16(W[k][n]); centsB = bf16(centroids)
// ---------------------------------------------------------------------------
__global__ __launch_bounds__(256) void k_prep(const float* __restrict__ W,
                                              const float* __restrict__ cents,
                                              unsigned short* __restrict__ Wt,
                                              unsigned short* __restrict__ centsB) {
  const int t = threadIdx.x;
  const int bid = blockIdx.x;
  if (bid < 256) {
    // 32x32 tile transpose of W (512x512)
    __shared__ float tile[32][33];
    const int k0 = (bid >> 4) << 5;
    const int n0 = (bid & 15) << 5;
    const int tx = t & 31, ty = t >> 5;  // 32 x 8
#pragma unroll
    for (int i = 0; i < 4; ++i) {
      int r = ty + i * 8;
      tile[r][tx] = W[(size_t)(k0 + r) * NDOUT + n0 + tx];
    }
    __syncthreads();
#pragma unroll
    for (int i = 0; i < 4; ++i) {
      int r = ty + i * 8;
      Wt[(size_t)(n0 + r) * NDIN + k0 + tx] = f2bf(tile[tx][r]);
    }
  } else {
    // cast centroids: 131072 floats, blocks 256..287, 16 per thread
    const int i0 = (bid - 256) * 4096 + t * 16;
#pragma unroll
    for (int j = 0; j < 4; ++j) {
      float4 v = *(const float4*)(cents + i0 + j * 4);
      unsigned short h0 = f2bf(v.x), h1 = f2bf(v.y), h2 = f2bf(v.z), h3 = f2bf(v.w);
      ushort4 h = make_ushort4(h0, h1, h2, h3);
      *(ushort4*)(centsB + i0 + j * 4) = h;
    }
  }
}

// ---------------------------------------------------------------------------
// Kernel 1: per (b,c) argmax_k <inputs[b,c,:], centroids[c,k,:]>
// 4 b's per thread as two b-pairs; centroids[c] staged in LDS (16 KB),
// register-double-buffered ds_read_b128 per k. Dot: serial d=0..15 fold per b
// (same association as the passing R4 kernel). Per acc-half tracking,
// strict > with ascending k => first-index tie (matches np.argmax).
// ---------------------------------------------------------------------------
__global__ __launch_bounds__(256, 4) void k_phase1(const float* __restrict__ inputs,
                                                   const float* __restrict__ cents,
                                                   float* __restrict__ negout,
                                                   float* __restrict__ codefout,
                                                   int* __restrict__ codeint) {
  __shared__ float4 lc[1040];   // 256 k x 4 float4 (=16 KB) + pad for dbuf over-read
  const int t = threadIdx.x;
  const int c = blockIdx.y;
  {
    const float4* cg = (const float4*)(cents + (size_t)c * NK * NDS);
#pragma unroll
    for (int i = 0; i < 4; ++i) lc[t + i * 256] = cg[t + i * 256];
    if (t < 16) lc[1024 + t] = f2v{0.0f, 0.0f}.x == 0.0f ? make_float4(0, 0, 0, 0) : make_float4(0, 0, 0, 0);
  }
  __syncthreads();

  const int b0 = blockIdx.x * 1024 + t;   // this thread: b0, +256, +512, +768

  // input pairs: p0[d] = {row(b0)[d], row(b0+256)[d]}, p1[d] = {row(+512)[d], row(+768)[d]}
  f2v p0[16], p1[16];
  {
    const float4* rA = (const float4*)(inputs + ((size_t)b0 * NC + c) * NDS);
    const float4* rB = (const float4*)(inputs + ((size_t)(b0 + 256) * NC + c) * NDS);
    const float4* rC = (const float4*)(inputs + ((size_t)(b0 + 512) * NC + c) * NDS);
    const float4* rD = (const float4*)(inputs + ((size_t)(b0 + 768) * NC + c) * NDS);
#pragma unroll
    for (int j = 0; j < 4; ++j) {
      float4 a = rA[j], b = rB[j], cc = rC[j], dd = rD[j];
      p0[4 * j + 0] = f2v{a.x, b.x};  p0[4 * j + 1] = f2v{a.y, b.y};
      p0[4 * j + 2] = f2v{a.z, b.z};  p0[4 * j + 3] = f2v{a.w, b.w};
      p1[4 * j + 0] = f2v{cc.x, dd.x}; p1[4 * j + 1] = f2v{cc.y, dd.y};
      p1[4 * j + 2] = f2v{cc.z, dd.z}; p1[4 * j + 3] = f2v{cc.w, dd.w};
    }
  }

  float b0x = -3.0e38f, b0y = -3.0e38f, b1x = -3.0e38f, b1y = -3.0e38f;
  int bk0x = 0, bk0y = 0, bk1x = 0, bk1y = 0;

#define DOT_TRACK(q0, q1, q2, q3, kk)                                          \
  do {                                                                         \
    f2v c01 = f2v{q0.x, q0.y}, c23 = f2v{q0.z, q0.w};                          \
    f2v c45 = f2v{q1.x, q1.y}, c67 = f2v{q1.z, q1.w};                          \
    f2v c89 = f2v{q2.x, q2.y}, cab = f2v{q2.z, q2.w};                          \
    f2v ccd = f2v{q3.x, q3.y}, cef = f2v{q3.z, q3.w};                          \
    f2v a0, a1;                                                                \
    PKMUL_LO(a0, p0[0], c01);   PKMUL_LO(a1, p1[0], c01);                      \
    PKFMA_HI(a0, p0[1], c01);   PKFMA_HI(a1, p1[1], c01);                      \
    PKFMA_LO(a0, p0[2], c23);   PKFMA_LO(a1, p1[2], c23);                      \
    PKFMA_HI(a0, p0[3], c23);   PKFMA_HI(a1, p1[3], c23);                      \
    PKFMA_LO(a0, p0[4], c45);   PKFMA_LO(a1, p1[4], c45);                      \
    PKFMA_HI(a0, p0[5], c45);   PKFMA_HI(a1, p1[5], c45);                      \
    PKFMA_LO(a0, p0[6], c67);   PKFMA_LO(a1, p1[6], c67);                      \
    PKFMA_HI(a0, p0[7], c67);   PKFMA_HI(a1, p1[7], c67);                      \
    PKFMA_LO(a0, p0[8], c89);   PKFMA_LO(a1, p1[8], c89);                      \
    PKFMA_HI(a0, p0[9], c89);   PKFMA_HI(a1, p1[9], c89);                      \
    PKFMA_LO(a0, p0[10], cab);  PKFMA_LO(a1, p1[10], cab);                     \
    PKFMA_HI(a0, p0[11], cab);  PKFMA_HI(a1, p1[11], cab);                     \
    PKFMA_LO(a0, p0[12], ccd);  PKFMA_LO(a1, p1[12], ccd);                     \
    PKFMA_HI(a0, p0[13], ccd);  PKFMA_HI(a1, p1[13], ccd);                     \
    PKFMA_LO(a0, p0[14], cef);  PKFMA_LO(a1, p1[14], cef);                     \
    PKFMA_HI(a0, p0[15], cef);  PKFMA_HI(a1, p1[15], cef);                     \
    bool g; float v;                                                           \
    v = a0.x; g = v > b0x; bk0x = g ? (kk) : bk0x; b0x = g ? v : b0x;          \
    v = a0.y; g = v > b0y; bk0y = g ? (kk) : bk0y; b0y = g ? v : b0y;          \
    v = a1.x; g = v > b1x; bk1x = g ? (kk) : bk1x; b1x = g ? v : b1x;          \
    v = a1.y; g = v > b1y; bk1y = g ? (kk) : bk1y; b1y = g ? v : b1y;          \
  } while (0)

  float4 qa0 = lc[0], qa1 = lc[1], qa2 = lc[2], qa3 = lc[3];
#pragma unroll 1
  for (int k = 0; k < NK; k += 2) {
    float4 qb0 = lc[(k + 1) * 4 + 0], qb1 = lc[(k + 1) * 4 + 1];
    float4 qb2 = lc[(k + 1) * 4 + 2], qb3 = lc[(k + 1) * 4 + 3];
    DOT_TRACK(qa0, qa1, qa2, qa3, k);
    qa0 = lc[(k + 2) * 4 + 0]; qa1 = lc[(k + 2) * 4 + 1];   // k=254 reads pad
    qa2 = lc[(k + 2) * 4 + 2]; qa3 = lc[(k + 2) * 4 + 3];
    DOT_TRACK(qb0, qb1, qb2, qb3, k + 1);
  }
#undef DOT_TRACK

  {
    size_t oA = (size_t)b0 * NC + c;
    size_t oB = (size_t)(b0 + 256) * NC + c;
    size_t oC = (size_t)(b0 + 512) * NC + c;
    size_t oD = (size_t)(b0 + 768) * NC + c;
    negout[oA] = -b0x;  codefout[oA] = (float)bk0x;  codeint[oA] = bk0x;
    negout[oB] = -b0y;  codefout[oB] = (float)bk0y;  codeint[oB] = bk0y;
    negout[oC] = -b1x;  codefout[oC] = (float)bk1x;  codeint[oC] = bk1x;
    negout[oD] = -b1y;  codefout[oD] = (float)bk1y;  codeint[oD] = bk1y;
  }
}

// ---------------------------------------------------------------------------
// Kernel 2: product = gather(centsB, codes) @ W   via bf16 MFMA
// 128x128 tile, BK=64, 4 waves (2x2 of 64x64), A gathered via global_load_lds
// ---------------------------------------------------------------------------
__global__ __launch_bounds__(256) void k_gemm(const unsigned short* __restrict__ centsB,
                                              const int* __restrict__ codeint,
                                              const unsigned short* __restrict__ Wt,
                                              float* __restrict__ out) {
  __shared__ __align__(16) unsigned short As[128 * 64];  // 16 KiB (XOR-swizzled)
  __shared__ __align__(16) unsigned short Bs[128 * 64];  // 16 KiB (XOR-swizzled)
  __shared__ int lcode[128 * 33];                        // codes, padded vs bank conflict

  const int t = threadIdx.x;
  const int l = t & 63;
  const int w = t >> 6;
  const int wm = w >> 1, wn = w & 1;
  const int m0 = blockIdx.x * 128;
  const int n0 = blockIdx.y * 128;

  // preload this block's codes: rows m0..m0+127, all 32 c (coalesced int4)
  {
    const int4* cp = (const int4*)(codeint + (size_t)m0 * NC);
#pragma unroll
    for (int i = 0; i < 4; ++i) {
      int idx = t + i * 256;          // int4 index; row = idx/8, col = (idx%8)*4
      int4 v = cp[idx];
      int row = idx >> 3, col = (idx & 7) * 4;
      lcode[row * 33 + col + 0] = v.x;
      lcode[row * 33 + col + 1] = v.y;
      lcode[row * 33 + col + 2] = v.z;
      lcode[row * 33 + col + 3] = v.w;
    }
  }

  f4v acc[4][4] = {};
  const int s = t & 7;        // 16B slot within a 128B row
  const int rq = t >> 3;      // 0..31: row within a 32-row staging chunk

  for (int kt = 0; kt < 8; ++kt) {
    __syncthreads();  // iter0: lcode visible; later: all frag reads of As/Bs done
    const int c0 = kt * 4;
    // ---- stage A (gathered): As[row][slot] = A[m0+row][kt*64 + (slot^(row&7))*8 ..]
#pragma unroll
    for (int i = 0; i < 4; ++i) {
      int lr = i * 32 + rq;
      int srcslot = s ^ (lr & 7);
      int cl = srcslot >> 1, half = srcslot & 1;
      int code = lcode[lr * 33 + c0 + cl];
      const unsigned short* gsrc =
          centsB + ((size_t)((c0 + cl) * NK + code) * NDS + half * 8);
      gload16(gsrc, (char*)As + i * 4096 + (w << 10));
    }
    // ---- stage B: Bs[n][slot] = Wt[n0+n][kt*64 + (slot^(n&7))*8 ..]
#pragma unroll
    for (int i = 0; i < 4; ++i) {
      int lr = i * 32 + rq;
      int k16 = s ^ (lr & 7);
      const unsigned short* gsrc = Wt + (size_t)(n0 + lr) * NDIN + kt * 64 + k16 * 8;
      gload16(gsrc, (char*)Bs + i * 4096 + (w << 10));
    }
    __syncthreads();  // compiler inserts vmcnt(0) drain: LDS tiles ready

    s8v af[4][2], bfr[4][2];
#pragma unroll
    for (int mf = 0; mf < 4; ++mf)
#pragma unroll
      for (int ks = 0; ks < 2; ++ks) {
        int row = wm * 64 + mf * 16 + (l & 15);
        int slot = ks * 4 + (l >> 4);
        af[mf][ks] = *(const s8v*)((const char*)As + row * 128 + ((slot ^ (row & 7)) << 4));
      }
#pragma unroll
    for (int nf = 0; nf < 4; ++nf)
#pragma unroll
      for (int ks = 0; ks < 2; ++ks) {
        int row = wn * 64 + nf * 16 + (l & 15);
        int slot = ks * 4 + (l >> 4);
        bfr[nf][ks] = *(const s8v*)((const char*)Bs + row * 128 + ((slot ^ (row & 7)) << 4));
      }
#pragma unroll
    for (int ks = 0; ks < 2; ++ks)
#pragma unroll
      for (int mf = 0; mf < 4; ++mf)
#pragma unroll
        for (int nf = 0; nf < 4; ++nf)
          acc[mf][nf] = __builtin_amdgcn_mfma_f32_16x16x32_bf16(
              af[mf][ks], bfr[nf][ks], acc[mf][nf], 0, 0, 0);
  }

  // epilogue: C[row][col], row=(l>>4)*4+r, col=l&15 within each 16x16 frag
#pragma unroll
  for (int mf = 0; mf < 4; ++mf)
#pragma unroll
    for (int nf = 0; nf < 4; ++nf)
#pragma unroll
      for (int r = 0; r < 4; ++r) {
        int row = m0 + wm * 64 + mf * 16 + (l >> 4) * 4 + r;
        int col = n0 + wn * 64 + nf * 16 + (l & 15);
        out[(size_t)row * NDOUT + col] = acc[mf][nf][r];
      }
}

// ---------------------------------------------------------------------------
extern "C" void kernel_launch(void* const* d_in, const int* in_sizes, int n_in,
                              void* d_out, int out_size, void* d_ws, size_t ws_size,
                              hipStream_t stream) {
  const float* inputs = (const float*)d_in[0];   // (B, C, 16) f32
  const float* cents  = (const float*)d_in[1];   // (C, K, 16) f32
  const float* W      = (const float*)d_in[2];   // (512, 512) f32

  float* out = (float*)d_out;
  float* negout   = out + (size_t)NB * NDOUT;            // (B, C)
  float* codefout = negout + (size_t)NB * NC;            // (B, C) as float values

  unsigned short* Wt     = (unsigned short*)d_ws;                          // 512 KiB
  unsigned short* centsB = (unsigned short*)((char*)d_ws + 512 * 1024);    // 256 KiB
  int* codeint           = (int*)((char*)d_ws + (1 << 20));                // 4 MiB

  k_prep<<<288, 256, 0, stream>>>(W, cents, Wt, centsB);
  k_phase1<<<dim3(NB / 1024, NC), 256, 0, stream>>>(inputs, cents, negout, codefout, codeint);
  k_gemm<<<dim3(NB / 128, NDOUT / 128), 256, 0, stream>>>(centsB, codeint, Wt, out);
}

// Round 6
// 162.532 us; speedup vs baseline: 1.0046x; 1.0046x over previous
//
#include <hip/hip_runtime.h>

// DPQ network: response argmax (k-paired pk_fma, op_sel b-select, SGPR centroids)
//            + codebook-gather GEMM (bf16 MFMA)
// B=32768, C=32, K=256, D_SUB=16, D_IN=512, D_OUT=512

#define NB 32768
#define NC 32
#define NK 256
#define NDS 16
#define NDIN 512
#define NDOUT 512

typedef __attribute__((ext_vector_type(8))) short s8v;   // 8 bf16 in 4 VGPRs
typedef __attribute__((ext_vector_type(4))) float f4v;   // MFMA accumulator
typedef __attribute__((ext_vector_type(2))) float f2v;   // packed f32 pair (v_pk_*_f32)

__device__ __forceinline__ unsigned short f2bf(float f) {
  unsigned int u = __float_as_uint(f);
  u += 0x7fffu + ((u >> 16) & 1u);   // RNE
  return (unsigned short)(u >> 16);
}

__device__ __forceinline__ void gload16(const void* g, void* l) {
  __builtin_amdgcn_global_load_lds(
      (const __attribute__((address_space(1))) void*)g,
      (__attribute__((address_space(3))) void*)l, 16, 0, 0);
}

// Packed f32 FMA, centroid k-pair in SGPR pair (src1: lo=even k, hi=odd k).
// src0 = input pair {bX_d, bY_d} (VGPR pair). _A broadcasts src0.lo (bX) to
// both output halves; _B broadcasts src0.hi (bY). acc = {dot_evenK, dot_oddK}.
// op_sel semantics on gfx950 VOP3P f32 validated by R4/R5 passing correctness.
#define PKMUL_A(acc, in, cp) \
  asm("v_pk_mul_f32 %0, %1, %2 op_sel:[0,0] op_sel_hi:[0,1]" : "=v"(acc) : "v"(in), "s"(cp))
#define PKMUL_B(acc, in, cp) \
  asm("v_pk_mul_f32 %0, %1, %2 op_sel:[1,0] op_sel_hi:[1,1]" : "=v"(acc) : "v"(in), "s"(cp))
#define PKFMA_A(acc, in, cp) \
  asm("v_pk_fma_f32 %0, %1, %2, %0 op_sel:[0,0,0] op_sel_hi:[0,1,1]" : "+v"(acc) : "v"(in), "s"(cp))
#define PKFMA_B(acc, in, cp) \
  asm("v_pk_fma_f32 %0, %1, %2, %0 op_sel:[1,0,0] op_sel_hi:[1,1,1]" : "+v"(acc) : "v"(in), "s"(cp))

// ---------------------------------------------------------------------------
// Kernel 0: Wt[n][k] = bf16(W[k][n]); centsB = bf16(centroids);
//           centsP[c][kp][d] = {cents[c][2kp][d], cents[c][2kp+1][d]}  (f2v)
// ---------------------------------------------------------------------------
__global__ __launch_bounds__(256) void k_prep(const float* __restrict__ W,
                                              const float* __restrict__ cents,
                                              unsigned short* __restrict__ Wt,
                                              unsigned short* __restrict__ centsB,
                                              f2v* __restrict__ centsP) {
  const int t = threadIdx.x;
  const int bid = blockIdx.x;
  if (bid < 256) {
    // 32x32 tile transpose of W (512x512)
    __shared__ float tile[32][33];
    const int k0 = (bid >> 4) << 5;
    const int n0 = (bid & 15) << 5;
    const int tx = t & 31, ty = t >> 5;  // 32 x 8
#pragma unroll
    for (int i = 0; i < 4; ++i) {
      int r = ty + i * 8;
      tile[r][tx] = W[(size_t)(k0 + r) * NDOUT + n0 + tx];
    }
    __syncthreads();
#pragma unroll
    for (int i = 0; i < 4; ++i) {
      int r = ty + i * 8;
      Wt[(size_t)(n0 + r) * NDIN + k0 + tx] = f2bf(tile[tx][r]);
    }
  } else if (bid < 288) {
    // cast centroids: 131072 floats, blocks 256..287, 16 per thread
    const int i0 = (bid - 256) * 4096 + t * 16;
#pragma unroll
    for (int j = 0; j < 4; ++j) {
      float4 v = *(const float4*)(cents + i0 + j * 4);
      unsigned short h0 = f2bf(v.x), h1 = f2bf(v.y), h2 = f2bf(v.z), h3 = f2bf(v.w);
      ushort4 h = make_ushort4(h0, h1, h2, h3);
      *(ushort4*)(centsB + i0 + j * 4) = h;
    }
  } else {
    // k-pair packing for phase1: blocks 288..319, one per c
    const int c = bid - 288;
    const int kp = t & 127;
    const int d0 = (t >> 7) * 8;
    const float* r0 = cents + ((size_t)c * NK + 2 * kp) * NDS + d0;
    const float* r1 = r0 + NDS;
    f2v* dst = centsP + ((size_t)c * 128 + kp) * NDS + d0;
#pragma unroll
    for (int j = 0; j < 8; ++j) dst[j] = f2v{r0[j], r1[j]};
  }
}

// ---------------------------------------------------------------------------
// Kernel 1: per (b,c) argmax_k <inputs[b,c,:], centroids[c,k,:]>
// 4 b's per thread as two NAMED f2v pair-sets (p*: {bA,bB}, q*: {bC,bD}) —
// no f2v arrays (they spill, R2/R5 evidence). Centroid k-pairs from SGPRs.
// Per kp: 64 pk_fma across 4 independent acc chains, then even/odd best
// tracking (strict >, ascending k). Final combine uses exact first-index
// tie rule to match np.argmax.
// ---------------------------------------------------------------------------
__global__ __launch_bounds__(256, 4) void k_phase1(const float* __restrict__ inputs,
                                                   const f2v* __restrict__ centsP,
                                                   float* __restrict__ negout,
                                                   float* __restrict__ codefout,
                                                   int* __restrict__ codeint) {
  const int t = threadIdx.x;
  const int c = blockIdx.y;
  const int b0 = blockIdx.x * 1024 + t;   // rows b0, +256, +512, +768

  f2v p0, p1, p2, p3, p4, p5, p6, p7, p8, p9, p10, p11, p12, p13, p14, p15;
  f2v q0, q1, q2, q3, q4, q5, q6, q7, q8, q9, q10, q11, q12, q13, q14, q15;
  {
    const float4* rA = (const float4*)(inputs + ((size_t)b0 * NC + c) * NDS);
    const float4* rB = (const float4*)(inputs + ((size_t)(b0 + 256) * NC + c) * NDS);
    const float4* rC = (const float4*)(inputs + ((size_t)(b0 + 512) * NC + c) * NDS);
    const float4* rD = (const float4*)(inputs + ((size_t)(b0 + 768) * NC + c) * NDS);
    float4 a, b;
    a = rA[0]; b = rB[0];
    p0 = f2v{a.x, b.x}; p1 = f2v{a.y, b.y}; p2 = f2v{a.z, b.z}; p3 = f2v{a.w, b.w};
    a = rA[1]; b = rB[1];
    p4 = f2v{a.x, b.x}; p5 = f2v{a.y, b.y}; p6 = f2v{a.z, b.z}; p7 = f2v{a.w, b.w};
    a = rA[2]; b = rB[2];
    p8 = f2v{a.x, b.x}; p9 = f2v{a.y, b.y}; p10 = f2v{a.z, b.z}; p11 = f2v{a.w, b.w};
    a = rA[3]; b = rB[3];
    p12 = f2v{a.x, b.x}; p13 = f2v{a.y, b.y}; p14 = f2v{a.z, b.z}; p15 = f2v{a.w, b.w};
    a = rC[0]; b = rD[0];
    q0 = f2v{a.x, b.x}; q1 = f2v{a.y, b.y}; q2 = f2v{a.z, b.z}; q3 = f2v{a.w, b.w};
    a = rC[1]; b = rD[1];
    q4 = f2v{a.x, b.x}; q5 = f2v{a.y, b.y}; q6 = f2v{a.z, b.z}; q7 = f2v{a.w, b.w};
    a = rC[2]; b = rD[2];
    q8 = f2v{a.x, b.x}; q9 = f2v{a.y, b.y}; q10 = f2v{a.z, b.z}; q11 = f2v{a.w, b.w};
    a = rC[3]; b = rD[3];
    q12 = f2v{a.x, b.x}; q13 = f2v{a.y, b.y}; q14 = f2v{a.z, b.z}; q15 = f2v{a.w, b.w};
  }

  // even/odd best tracks per b (A,B,C,D)
  float bEA = -3.0e38f, bOA = -3.0e38f, bEB = -3.0e38f, bOB = -3.0e38f;
  float bEC = -3.0e38f, bOC = -3.0e38f, bED = -3.0e38f, bOD = -3.0e38f;
  int kEA = 0, kOA = 1, kEB = 0, kOB = 1, kEC = 0, kOC = 1, kED = 0, kOD = 1;

  const f2v* cp = centsP + (size_t)c * (128 * NDS);   // uniform across block

#define STEP(d)                                                                \
  PKFMA_A(accA, p##d, s##d); PKFMA_B(accB, p##d, s##d);                        \
  PKFMA_A(accC, q##d, s##d); PKFMA_B(accD, q##d, s##d);

#pragma unroll 2
  for (int kp = 0; kp < 128; ++kp) {
    const f2v* pk = cp + kp * NDS;                    // uniform -> s_load
    f2v s0 = pk[0], s1 = pk[1], s2 = pk[2], s3 = pk[3];
    f2v s4 = pk[4], s5 = pk[5], s6 = pk[6], s7 = pk[7];
    f2v s8 = pk[8], s9 = pk[9], s10 = pk[10], s11 = pk[11];
    f2v s12 = pk[12], s13 = pk[13], s14 = pk[14], s15 = pk[15];

    f2v accA, accB, accC, accD;
    PKMUL_A(accA, p0, s0); PKMUL_B(accB, p0, s0);
    PKMUL_A(accC, q0, s0); PKMUL_B(accD, q0, s0);
    STEP(1)  STEP(2)  STEP(3)  STEP(4)  STEP(5)
    STEP(6)  STEP(7)  STEP(8)  STEP(9)  STEP(10)
    STEP(11) STEP(12) STEP(13) STEP(14) STEP(15)

    const int k0 = kp * 2;
    bool g;
    g = accA.x > bEA; kEA = g ? k0 : kEA;     bEA = g ? accA.x : bEA;
    g = accA.y > bOA; kOA = g ? k0 + 1 : kOA; bOA = g ? accA.y : bOA;
    g = accB.x > bEB; kEB = g ? k0 : kEB;     bEB = g ? accB.x : bEB;
    g = accB.y > bOB; kOB = g ? k0 + 1 : kOB; bOB = g ? accB.y : bOB;
    g = accC.x > bEC; kEC = g ? k0 : kEC;     bEC = g ? accC.x : bEC;
    g = accC.y > bOC; kOC = g ? k0 + 1 : kOC; bOC = g ? accC.y : bOC;
    g = accD.x > bED; kED = g ? k0 : kED;     bED = g ? accD.x : bED;
    g = accD.y > bOD; kOD = g ? k0 + 1 : kOD; bOD = g ? accD.y : bOD;
  }
#undef STEP

  // combine even/odd tracks with np.argmax first-index tie rule
#define COMBINE(bE, kE, bO, kO, bb, kk)                                        \
  {                                                                            \
    bool takeO = (bO > bE) || ((bO == bE) && (kO < kE));                       \
    bb = takeO ? bO : bE;                                                      \
    kk = takeO ? kO : kE;                                                      \
  }
  float vA, vB, vC, vD; int iA, iB, iC, iD;
  COMBINE(bEA, kEA, bOA, kOA, vA, iA)
  COMBINE(bEB, kEB, bOB, kOB, vB, iB)
  COMBINE(bEC, kEC, bOC, kOC, vC, iC)
  COMBINE(bED, kED, bOD, kOD, vD, iD)
#undef COMBINE

  {
    size_t oA = (size_t)b0 * NC + c;
    size_t oB = (size_t)(b0 + 256) * NC + c;
    size_t oC = (size_t)(b0 + 512) * NC + c;
    size_t oD = (size_t)(b0 + 768) * NC + c;
    negout[oA] = -vA;  codefout[oA] = (float)iA;  codeint[oA] = iA;
    negout[oB] = -vB;  codefout[oB] = (float)iB;  codeint[oB] = iB;
    negout[oC] = -vC;  codefout[oC] = (float)iC;  codeint[oC] = iC;
    negout[oD] = -vD;  codefout[oD] = (float)iD;  codeint[oD] = iD;
  }
}

// ---------------------------------------------------------------------------
// Kernel 2: product = gather(centsB, codes) @ W   via bf16 MFMA
// 128x128 tile, BK=64, 4 waves (2x2 of 64x64), A gathered via global_load_lds
// ---------------------------------------------------------------------------
__global__ __launch_bounds__(256) void k_gemm(const unsigned short* __restrict__ centsB,
                                              const int* __restrict__ codeint,
                                              const unsigned short* __restrict__ Wt,
                                              float* __restrict__ out) {
  __shared__ __align__(16) unsigned short As[128 * 64];  // 16 KiB (XOR-swizzled)
  __shared__ __align__(16) unsigned short Bs[128 * 64];  // 16 KiB (XOR-swizzled)
  __shared__ int lcode[128 * 33];                        // codes, padded vs bank conflict

  const int t = threadIdx.x;
  const int l = t & 63;
  const int w = t >> 6;
  const int wm = w >> 1, wn = w & 1;
  const int m0 = blockIdx.x * 128;
  const int n0 = blockIdx.y * 128;

  // preload this block's codes: rows m0..m0+127, all 32 c (coalesced int4)
  {
    const int4* cp = (const int4*)(codeint + (size_t)m0 * NC);
#pragma unroll
    for (int i = 0; i < 4; ++i) {
      int idx = t + i * 256;          // int4 index; row = idx/8, col = (idx%8)*4
      int4 v = cp[idx];
      int row = idx >> 3, col = (idx & 7) * 4;
      lcode[row * 33 + col + 0] = v.x;
      lcode[row * 33 + col + 1] = v.y;
      lcode[row * 33 + col + 2] = v.z;
      lcode[row * 33 + col + 3] = v.w;
    }
  }

  f4v acc[4][4] = {};
  const int s = t & 7;        // 16B slot within a 128B row
  const int rq = t >> 3;      // 0..31: row within a 32-row staging chunk

  for (int kt = 0; kt < 8; ++kt) {
    __syncthreads();  // iter0: lcode visible; later: all frag reads of As/Bs done
    const int c0 = kt * 4;
    // ---- stage A (gathered): As[row][slot] = A[m0+row][kt*64 + (slot^(row&7))*8 ..]
#pragma unroll
    for (int i = 0; i < 4; ++i) {
      int lr = i * 32 + rq;
      int srcslot = s ^ (lr & 7);
      int cl = srcslot >> 1, half = srcslot & 1;
      int code = lcode[lr * 33 + c0 + cl];
      const unsigned short* gsrc =
          centsB + ((size_t)((c0 + cl) * NK + code) * NDS + half * 8);
      gload16(gsrc, (char*)As + i * 4096 + (w << 10));
    }
    // ---- stage B: Bs[n][slot] = Wt[n0+n][kt*64 + (slot^(n&7))*8 ..]
#pragma unroll
    for (int i = 0; i < 4; ++i) {
      int lr = i * 32 + rq;
      int k16 = s ^ (lr & 7);
      const unsigned short* gsrc = Wt + (size_t)(n0 + lr) * NDIN + kt * 64 + k16 * 8;
      gload16(gsrc, (char*)Bs + i * 4096 + (w << 10));
    }
    __syncthreads();  // compiler inserts vmcnt(0) drain: LDS tiles ready

    s8v af[4][2], bfr[4][2];
#pragma unroll
    for (int mf = 0; mf < 4; ++mf)
#pragma unroll
      for (int ks = 0; ks < 2; ++ks) {
        int row = wm * 64 + mf * 16 + (l & 15);
        int slot = ks * 4 + (l >> 4);
        af[mf][ks] = *(const s8v*)((const char*)As + row * 128 + ((slot ^ (row & 7)) << 4));
      }
#pragma unroll
    for (int nf = 0; nf < 4; ++nf)
#pragma unroll
      for (int ks = 0; ks < 2; ++ks) {
        int row = wn * 64 + nf * 16 + (l & 15);
        int slot = ks * 4 + (l >> 4);
        bfr[nf][ks] = *(const s8v*)((const char*)Bs + row * 128 + ((slot ^ (row & 7)) << 4));
      }
#pragma unroll
    for (int ks = 0; ks < 2; ++ks)
#pragma unroll
      for (int mf = 0; mf < 4; ++mf)
#pragma unroll
        for (int nf = 0; nf < 4; ++nf)
          acc[mf][nf] = __builtin_amdgcn_mfma_f32_16x16x32_bf16(
              af[mf][ks], bfr[nf][ks], acc[mf][nf], 0, 0, 0);
  }

  // epilogue: C[row][col], row=(l>>4)*4+r, col=l&15 within each 16x16 frag
#pragma unroll
  for (int mf = 0; mf < 4; ++mf)
#pragma unroll
    for (int nf = 0; nf < 4; ++nf)
#pragma unroll
      for (int r = 0; r < 4; ++r) {
        int row = m0 + wm * 64 + mf * 16 + (l >> 4) * 4 + r;
        int col = n0 + wn * 64 + nf * 16 + (l & 15);
        out[(size_t)row * NDOUT + col] = acc[mf][nf][r];
      }
}

// ---------------------------------------------------------------------------
extern "C" void kernel_launch(void* const* d_in, const int* in_sizes, int n_in,
                              void* d_out, int out_size, void* d_ws, size_t ws_size,
                              hipStream_t stream) {
  const float* inputs = (const float*)d_in[0];   // (B, C, 16) f32
  const float* cents  = (const float*)d_in[1];   // (C, K, 16) f32
  const float* W      = (const float*)d_in[2];   // (512, 512) f32

  float* out = (float*)d_out;
  float* negout   = out + (size_t)NB * NDOUT;            // (B, C)
  float* codefout = negout + (size_t)NB * NC;            // (B, C) as float values

  unsigned short* Wt     = (unsigned short*)d_ws;                          // 512 KiB
  unsigned short* centsB = (unsigned short*)((char*)d_ws + 512 * 1024);    // 256 KiB
  int* codeint           = (int*)((char*)d_ws + (1 << 20));                // 4 MiB
  f2v* centsP            = (f2v*)((char*)d_ws + 5 * (1 << 20));            // 512 KiB

  k_prep<<<320, 256, 0, stream>>>(W, cents, Wt, centsB, centsP);
  k_phase1<<<dim3(NB / 1024, NC), 256, 0, stream>>>(inputs, centsP, negout, codefout, codeint);
  k_gemm<<<dim3(NB / 128, NDOUT / 128), 256, 0, stream>>>(centsB, codeint, Wt, out);
}